// Round 14
// baseline (295.088 us; speedup 1.0000x reference)
//
#include <hip/hip_runtime.h>
#include <hip/hip_bf16.h>
#include <hip/hip_fp16.h>

#define N_NODES 100000
#define N_EDGES 1600000
#define NBUCK ((N_NODES + 255) >> 8)   // 391 buckets of 256 nodes
#define CAP 8192                        // fixed region capacity per bucket (mean ~4096)
#define NQ (N_NODES / 4)                // 25000 quartets

typedef _Float16 f16x2 __attribute__((ext_vector_type(2)));

__device__ inline float2 h2_to_f2(unsigned int u) {
    __half2 h = *reinterpret_cast<__half2*>(&u);
    return __half22float2(h);
}
__device__ inline f16x2 uf2(unsigned int u) {
    union { unsigned int u; f16x2 h; } v;
    v.u = u;
    return v.h;
}
#if __has_builtin(__builtin_amdgcn_fdot2)
#define DOT2(a, b, c) __builtin_amdgcn_fdot2((a), (b), (c), false)
#else
__device__ inline float DOT2(f16x2 a, f16x2 b, float c) {
    return c + (float)a.x * (float)b.x + (float)a.y * (float)b.y;
}
#endif

// ---------------------------------------------------------------------------
// Zero bcursor + gsum (tiny; NOT hipMemsetAsync — rocclr blit node overhead)
// ---------------------------------------------------------------------------
__global__ void k_zero(int* __restrict__ p, int n) {
    for (int i = threadIdx.x; i < n; i += 256) p[i] = 0;
}

// ---------------------------------------------------------------------------
// CSR build pass 1: stage edges into fixed-capacity bucket regions.
// ---------------------------------------------------------------------------
__global__ __launch_bounds__(256) void k_stage(const int* __restrict__ src,
                                               const int* __restrict__ dst,
                                               int* __restrict__ bcursor,
                                               unsigned int* __restrict__ stage) {
    __shared__ int h[NBUCK];
    __shared__ int base[NBUCK];
    __shared__ int cur[NBUCK];
    const int epb = (N_EDGES + gridDim.x - 1) / gridDim.x;
    const int c0 = blockIdx.x * epb;
    const int c1 = (c0 + epb < N_EDGES) ? (c0 + epb) : N_EDGES;

    for (int i = threadIdx.x; i < NBUCK; i += 256) { h[i] = 0; cur[i] = 0; }
    __syncthreads();
    for (int e = c0 + threadIdx.x; e < c1; e += 256)
        atomicAdd(&h[dst[e] >> 8], 1);
    __syncthreads();
    for (int i = threadIdx.x; i < NBUCK; i += 256)
        base[i] = h[i] ? atomicAdd(&bcursor[i], h[i]) : 0;
    __syncthreads();
    for (int e = c0 + threadIdx.x; e < c1; e += 256) {
        int d = dst[e];
        int b = d >> 8;
        int pos = base[b] + atomicAdd(&cur[b], 1);
        if (pos < CAP)  // overflow guard (P ~ 0 for this graph)
            stage[b * CAP + pos] = ((unsigned int)(d & 255) << 17) | (unsigned int)src[e];
    }
}

// ---------------------------------------------------------------------------
// CSR build pass 2: one block (512 thr) per bucket; LDS counting-sort IN
// PLACE. Emits row_start[node] = b*CAP + local_excl_offset and deg[node].
// ---------------------------------------------------------------------------
__global__ __launch_bounds__(512) void k_bsort(unsigned int* __restrict__ stage,
                                               const int* __restrict__ bcursor,
                                               int* __restrict__ row_start,
                                               int* __restrict__ deg) {
    __shared__ int off[256];
    __shared__ int cur[256];
    __shared__ unsigned int out[CAP];
    const int b = blockIdx.x;
    int cnt = bcursor[b];
    if (cnt > CAP) cnt = CAP;
    const int s = b * CAP;
    const int tid = threadIdx.x;

    if (tid < 256) cur[tid] = 0;
    __syncthreads();
    for (int i = tid; i < cnt; i += 512)
        atomicAdd(&cur[stage[s + i] >> 17], 1);
    __syncthreads();
    int v = 0;
    if (tid < 256) {
        v = cur[tid];
        off[tid] = v;
    }
    __syncthreads();
    for (int d = 1; d < 256; d <<= 1) {
        int t = 0;
        if (tid < 256 && tid >= d) t = off[tid - d];
        __syncthreads();
        if (tid < 256) off[tid] += t;
        __syncthreads();
    }
    if (tid < 256) {
        int ex = off[tid] - v;
        off[tid] = ex;
        cur[tid] = 0;
        int node = b * 256 + tid;
        if (node < N_NODES) {
            row_start[node] = s + ex;
            deg[node] = v;
        }
    }
    __syncthreads();

    for (int i = tid; i < cnt; i += 512) {
        unsigned int p = stage[s + i];
        int l = p >> 17;
        int pos = off[l] + atomicAdd(&cur[l], 1);
        out[pos] = p & 0x1FFFFu;
    }
    __syncthreads();
    for (int i = tid; i < cnt; i += 512)
        stage[s + i] = out[i];
}

// ---------------------------------------------------------------------------
// Layer 1 fused: one wave per node, 8 neighbors per load, shfl-reduce,
// 8->64 MLP with weights in regs, write h1 as fp16.
// ---------------------------------------------------------------------------
__global__ __launch_bounds__(256) void layer1(
    const float* __restrict__ x, const int* __restrict__ row_start,
    const int* __restrict__ deg, const int* __restrict__ csr,
    const float* __restrict__ W1l, const float* __restrict__ b1,
    const float* __restrict__ W1r, __half* __restrict__ h1h) {
    const int lane = threadIdx.x & 63;
    const int g = lane >> 3;
    const int sub = lane & 7;

    float wl1[8], wr1[8];
#pragma unroll
    for (int k = 0; k < 8; k++) {
        wl1[k] = W1l[k * 64 + lane];
        wr1[k] = W1r[k * 64 + lane];
    }
    float bv = b1[lane];
    asm volatile("" ::: "memory");

    const int gwid = (blockIdx.x * blockDim.x + threadIdx.x) >> 6;
    const int nwaves = (gridDim.x * blockDim.x) >> 6;

    for (int node = gwid; node < N_NODES; node += nwaves) {
        int rs = row_start[node];
        int dg = deg[node];
        int re = rs + dg;
        float acc = 0.0f;
        int t = rs;
        for (; t + 16 <= re; t += 16) {
            int i0 = csr[t + g];
            int i1 = csr[t + 8 + g];
            acc += x[i0 * 8 + sub] + x[i1 * 8 + sub];
        }
        for (; t + 8 <= re; t += 8) {
            int i0 = csr[t + g];
            acc += x[i0 * 8 + sub];
        }
        int r = re - t;
        if (r > 0) {
            int ii = csr[(t + g < re) ? (t + g) : (re - 1)];
            float v = x[ii * 8 + sub];
            if (g < r) acc += v;
        }
        acc += __shfl_xor(acc, 8);
        acc += __shfl_xor(acc, 16);
        acc += __shfl_xor(acc, 32);
        float inv = 1.0f / fmaxf((float)dg, 1.0f);
        float mean = acc * inv;
        float xself = x[node * 8 + sub];
        float m[8], xk[8];
#pragma unroll
        for (int k = 0; k < 8; k++) {
            m[k]  = __shfl(mean, k);
            xk[k] = __shfl(xself, k);
        }
        float a = bv;
#pragma unroll
        for (int k = 0; k < 8; k++)
            a += m[k] * wl1[k] + xk[k] * wr1[k];
        h1h[node * 64 + lane] = __float2half(fmaxf(a, 0.0f));
    }
}

// ---------------------------------------------------------------------------
// Layer 2 aggregation (round-12 proven version): one wave per node, fp16
// rows, 4 neighbors per load, 2x unrolled. Output mean2 as fp16.
// ---------------------------------------------------------------------------
__global__ __launch_bounds__(256) void agg2(
    const __half* __restrict__ h1h, const int* __restrict__ row_start,
    const int* __restrict__ deg, const int* __restrict__ csr,
    __half* __restrict__ mean2h) {
    const int lane = threadIdx.x & 63;
    const int g = lane >> 4;
    const int sub = lane & 15;

    const int gwid = (blockIdx.x * blockDim.x + threadIdx.x) >> 6;
    const int nwaves = (gridDim.x * blockDim.x) >> 6;

    for (int node = gwid; node < N_NODES; node += nwaves) {
        int rs = row_start[node];
        int dg = deg[node];
        int re = rs + dg;
        float4 acc = {0.f, 0.f, 0.f, 0.f};
        int t = rs;
        for (; t + 8 <= re; t += 8) {
            int i0 = csr[t + g];
            int i1 = csr[t + 4 + g];
            uint2 a = *(const uint2*)(h1h + i0 * 64 + sub * 4);
            uint2 b = *(const uint2*)(h1h + i1 * 64 + sub * 4);
            float2 a0 = h2_to_f2(a.x), a1 = h2_to_f2(a.y);
            float2 b0 = h2_to_f2(b.x), b1 = h2_to_f2(b.y);
            acc.x += a0.x + b0.x; acc.y += a0.y + b0.y;
            acc.z += a1.x + b1.x; acc.w += a1.y + b1.y;
        }
        for (; t + 4 <= re; t += 4) {
            int i0 = csr[t + g];
            uint2 a = *(const uint2*)(h1h + i0 * 64 + sub * 4);
            float2 a0 = h2_to_f2(a.x), a1 = h2_to_f2(a.y);
            acc.x += a0.x; acc.y += a0.y; acc.z += a1.x; acc.w += a1.y;
        }
        int r = re - t;
        if (r > 0) {
            int ii = csr[(t + g < re) ? (t + g) : (re - 1)];
            uint2 a = *(const uint2*)(h1h + ii * 64 + sub * 4);
            if (g < r) {
                float2 a0 = h2_to_f2(a.x), a1 = h2_to_f2(a.y);
                acc.x += a0.x; acc.y += a0.y; acc.z += a1.x; acc.w += a1.y;
            }
        }
#pragma unroll
        for (int m = 16; m <= 32; m <<= 1) {
            acc.x += __shfl_xor(acc.x, m);
            acc.y += __shfl_xor(acc.y, m);
            acc.z += __shfl_xor(acc.z, m);
            acc.w += __shfl_xor(acc.w, m);
        }
        float inv = 1.0f / fmaxf((float)dg, 1.0f);
        if (lane < 16) {
            __half2 o0 = __floats2half2_rn(acc.x * inv, acc.y * inv);
            __half2 o1 = __floats2half2_rn(acc.z * inv, acc.w * inv);
            uint2 pk;
            pk.x = *(unsigned int*)&o0;
            pk.y = *(unsigned int*)&o1;
            *(uint2*)(mean2h + node * 64 + sub * 4) = pk;
        }
    }
}

// ---------------------------------------------------------------------------
// Layer 2 MLP + global mean pool. Quartet-per-wave, double-buffered private
// LDS staging, packed half2 weights via v_dot2_f32_f16.
// ---------------------------------------------------------------------------
__global__ __launch_bounds__(256) void mlp2(
    const __half* __restrict__ mean2h, const __half* __restrict__ h1h,
    const float* __restrict__ W2l, const float* __restrict__ b2,
    const float* __restrict__ W2r, float* __restrict__ gsum) {
    __shared__ __align__(16) unsigned short sh[4][2][512];
    __shared__ float part[4][64];
    const int tid = threadIdx.x;
    const int lane = tid & 63;
    const int w = tid >> 6;

    f16x2 w2[64];
#pragma unroll
    for (int k2 = 0; k2 < 32; k2++) {
        f16x2 t;
        t.x = (_Float16)W2l[(2 * k2) * 64 + lane];
        t.y = (_Float16)W2l[(2 * k2 + 1) * 64 + lane];
        w2[k2] = t;
        f16x2 u;
        u.x = (_Float16)W2r[(2 * k2) * 64 + lane];
        u.y = (_Float16)W2r[(2 * k2 + 1) * 64 + lane];
        w2[32 + k2] = u;
    }
    float bv = b2[lane];
    asm volatile("" ::: "memory");

    const int n = lane >> 4;
    const int r = (lane >> 3) & 1;
    const int c = lane & 7;
    const __half* sbase = r ? h1h : mean2h;

    const int gwid = (blockIdx.x * blockDim.x + tid) >> 6;
    const int nwaves = (gridDim.x * blockDim.x) >> 6;
    float pool = 0.0f;

    int q = gwid;
    uint4 cur = {0, 0, 0, 0};
    if (q < NQ)
        cur = *(const uint4*)(sbase + (size_t)(q * 4 + n) * 64 + c * 8);
    int p = 0;
    while (q < NQ) {
        *(uint4*)&sh[w][p][lane * 8] = cur;
        int qn = q + nwaves;
        uint4 nxt = {0, 0, 0, 0};
        if (qn < NQ)
            nxt = *(const uint4*)(sbase + (size_t)(qn * 4 + n) * 64 + c * 8);
        const uint4* rows = (const uint4*)&sh[w][p][0];
        float a0 = bv, a1 = bv, a2 = bv, a3 = bv;
#pragma unroll
        for (int cc = 0; cc < 16; cc++) {
            uint4 r0 = rows[cc];
            uint4 r1 = rows[16 + cc];
            uint4 r2 = rows[32 + cc];
            uint4 r3 = rows[48 + cc];
            f16x2 wa = w2[cc * 4 + 0], wb = w2[cc * 4 + 1];
            f16x2 wc = w2[cc * 4 + 2], wd = w2[cc * 4 + 3];
            a0 = DOT2(uf2(r0.x), wa, a0); a0 = DOT2(uf2(r0.y), wb, a0);
            a0 = DOT2(uf2(r0.z), wc, a0); a0 = DOT2(uf2(r0.w), wd, a0);
            a1 = DOT2(uf2(r1.x), wa, a1); a1 = DOT2(uf2(r1.y), wb, a1);
            a1 = DOT2(uf2(r1.z), wc, a1); a1 = DOT2(uf2(r1.w), wd, a1);
            a2 = DOT2(uf2(r2.x), wa, a2); a2 = DOT2(uf2(r2.y), wb, a2);
            a2 = DOT2(uf2(r2.z), wc, a2); a2 = DOT2(uf2(r2.w), wd, a2);
            a3 = DOT2(uf2(r3.x), wa, a3); a3 = DOT2(uf2(r3.y), wb, a3);
            a3 = DOT2(uf2(r3.z), wc, a3); a3 = DOT2(uf2(r3.w), wd, a3);
        }
        pool += fmaxf(a0, 0.0f) + fmaxf(a1, 0.0f) +
                fmaxf(a2, 0.0f) + fmaxf(a3, 0.0f);
        cur = nxt;
        p ^= 1;
        q = qn;
    }

    part[w][lane] = pool;
    __syncthreads();
    if (tid < 64)
        atomicAdd(&gsum[tid],
                  part[0][tid] + part[1][tid] + part[2][tid] + part[3][tid]);
}

// ---------------------------------------------------------------------------
// Head
// ---------------------------------------------------------------------------
__global__ void head(const float* __restrict__ gsum,
                     const float* __restrict__ fc1W, const float* __restrict__ fc1b,
                     const float* __restrict__ fc2W, const float* __restrict__ fc2b,
                     float* __restrict__ out) {
    __shared__ float g[64];
    __shared__ float a1[64];
    __shared__ float a2[10];
    int j = threadIdx.x;
    g[j] = gsum[j] * (1.0f / (float)N_NODES);
    __syncthreads();
    float acc = fc1b[j];
    for (int k = 0; k < 64; k++) acc += g[k] * fc1W[k * 64 + j];
    a1[j] = fmaxf(acc, 0.0f);
    __syncthreads();
    if (j < 10) {
        float acc2 = fc2b[j];
        for (int k = 0; k < 64; k++) acc2 += a1[k] * fc2W[k * 10 + j];
        a2[j] = acc2;
    }
    __syncthreads();
    if (j == 0) {
        float mx = -1e30f;
        for (int i = 0; i < 10; i++) mx = fmaxf(mx, a2[i]);
        float s = 0.0f;
        float e[10];
        for (int i = 0; i < 10; i++) {
            e[i] = expf(a2[i] - mx);
            s += e[i];
        }
        float invs = 1.0f / s;
        for (int i = 0; i < 10; i++) out[i] = e[i] * invs;
    }
}

extern "C" void kernel_launch(void* const* d_in, const int* in_sizes, int n_in,
                              void* d_out, int out_size, void* d_ws, size_t ws_size,
                              hipStream_t stream) {
    const float* x    = (const float*)d_in[0];
    const int*   ei   = (const int*)d_in[1];
    const float* W1l  = (const float*)d_in[2];
    const float* b1   = (const float*)d_in[3];
    const float* W1r  = (const float*)d_in[4];
    const float* W2l  = (const float*)d_in[5];
    const float* b2   = (const float*)d_in[6];
    const float* W2r  = (const float*)d_in[7];
    const float* fc1W = (const float*)d_in[8];
    const float* fc1b = (const float*)d_in[9];
    const float* fc2W = (const float*)d_in[10];
    const float* fc2b = (const float*)d_in[11];
    float* out = (float*)d_out;

    const int* src = ei;
    const int* dst = ei + N_EDGES;

    // workspace layout:
    //   h1h (N*64 half, 12.8MB) | stage/csr (NBUCK*CAP uint, 12.8MB) |
    //   mean2h (N*64 half, 12.8MB) | row_start (N) | deg (N) | bcursor (NB) | gsum
    __half* h1h    = (__half*)d_ws;
    unsigned int* stage = (unsigned int*)(h1h + (size_t)N_NODES * 64);
    int* csr       = (int*)stage;   // sorted in place by k_bsort
    __half* mean2h = (__half*)(stage + (size_t)NBUCK * CAP);
    int* row_start = (int*)(mean2h + (size_t)N_NODES * 64);
    int* deg       = row_start + N_NODES;
    int* bcursor   = deg + N_NODES;
    float* gsum    = (float*)(bcursor + NBUCK);

    // zero bcursor + gsum (adjacent)
    k_zero<<<1, 256, 0, stream>>>(bcursor, NBUCK + 64);

    k_stage<<<512, 256, 0, stream>>>(src, dst, bcursor, stage);
    k_bsort<<<NBUCK, 512, 0, stream>>>(stage, bcursor, row_start, deg);
    layer1<<<2048, 256, 0, stream>>>(x, row_start, deg, csr, W1l, b1, W1r, h1h);
    agg2<<<2048, 256, 0, stream>>>(h1h, row_start, deg, csr, mean2h);
    mlp2<<<512, 256, 0, stream>>>(mean2h, h1h, W2l, b2, W2r, gsum);
    head<<<1, 64, 0, stream>>>(gsum, fc1W, fc1b, fc2W, fc2b, out);

    // ---- MEASUREMENT (this round only): 4 idempotent agg2 replays.
    // agg2 re-writes mean2h with identical values; output unaffected.
    // agg2_time = (dur_us - 143.8)/4; if >43us it also surfaces in top-5.
    agg2<<<2048, 256, 0, stream>>>(h1h, row_start, deg, csr, mean2h);
    agg2<<<2048, 256, 0, stream>>>(h1h, row_start, deg, csr, mean2h);
    agg2<<<2048, 256, 0, stream>>>(h1h, row_start, deg, csr, mean2h);
    agg2<<<2048, 256, 0, stream>>>(h1h, row_start, deg, csr, mean2h);
}

// Round 15
// 149.863 us; speedup vs baseline: 1.9691x; 1.9691x over previous
//
#include <hip/hip_runtime.h>
#include <hip/hip_bf16.h>
#include <hip/hip_fp16.h>

#define N_NODES 100000
#define N_EDGES 1600000
#define NBUCK ((N_NODES + 255) >> 8)   // 391 buckets of 256 nodes
#define CAP 8192                        // fixed region capacity per bucket (mean ~4096)
#define NQ (N_NODES / 4)                // 25000 quartets

typedef _Float16 f16x2 __attribute__((ext_vector_type(2)));

__device__ inline float2 h2_to_f2(unsigned int u) {
    __half2 h = *reinterpret_cast<__half2*>(&u);
    return __half22float2(h);
}
__device__ inline f16x2 uf2(unsigned int u) {
    union { unsigned int u; f16x2 h; } v;
    v.u = u;
    return v.h;
}
#if __has_builtin(__builtin_amdgcn_fdot2)
#define DOT2(a, b, c) __builtin_amdgcn_fdot2((a), (b), (c), false)
#else
__device__ inline float DOT2(f16x2 a, f16x2 b, float c) {
    return c + (float)a.x * (float)b.x + (float)a.y * (float)b.y;
}
#endif

// decode a uint4 (8 fp16) and accumulate into acc[8]
__device__ inline void h8_add(uint4 a, float* acc) {
    float2 f0 = h2_to_f2(a.x), f1 = h2_to_f2(a.y);
    float2 f2 = h2_to_f2(a.z), f3 = h2_to_f2(a.w);
    acc[0] += f0.x; acc[1] += f0.y; acc[2] += f1.x; acc[3] += f1.y;
    acc[4] += f2.x; acc[5] += f2.y; acc[6] += f3.x; acc[7] += f3.y;
}

// ---------------------------------------------------------------------------
// Zero bcursor + gsum (tiny; NOT hipMemsetAsync — rocclr blit node overhead)
// ---------------------------------------------------------------------------
__global__ void k_zero(int* __restrict__ p, int n) {
    for (int i = threadIdx.x; i < n; i += 256) p[i] = 0;
}

// ---------------------------------------------------------------------------
// CSR build pass 1: stage edges into fixed-capacity bucket regions.
// ---------------------------------------------------------------------------
__global__ __launch_bounds__(256) void k_stage(const int* __restrict__ src,
                                               const int* __restrict__ dst,
                                               int* __restrict__ bcursor,
                                               unsigned int* __restrict__ stage) {
    __shared__ int h[NBUCK];
    __shared__ int base[NBUCK];
    __shared__ int cur[NBUCK];
    const int epb = (N_EDGES + gridDim.x - 1) / gridDim.x;
    const int c0 = blockIdx.x * epb;
    const int c1 = (c0 + epb < N_EDGES) ? (c0 + epb) : N_EDGES;

    for (int i = threadIdx.x; i < NBUCK; i += 256) { h[i] = 0; cur[i] = 0; }
    __syncthreads();
    for (int e = c0 + threadIdx.x; e < c1; e += 256)
        atomicAdd(&h[dst[e] >> 8], 1);
    __syncthreads();
    for (int i = threadIdx.x; i < NBUCK; i += 256)
        base[i] = h[i] ? atomicAdd(&bcursor[i], h[i]) : 0;
    __syncthreads();
    for (int e = c0 + threadIdx.x; e < c1; e += 256) {
        int d = dst[e];
        int b = d >> 8;
        int pos = base[b] + atomicAdd(&cur[b], 1);
        if (pos < CAP)  // overflow guard (P ~ 0 for this graph)
            stage[b * CAP + pos] = ((unsigned int)(d & 255) << 17) | (unsigned int)src[e];
    }
}

// ---------------------------------------------------------------------------
// CSR build pass 2: one block (512 thr) per bucket; LDS counting-sort IN
// PLACE. Emits row_start[node] = b*CAP + local_excl_offset and deg[node].
// ---------------------------------------------------------------------------
__global__ __launch_bounds__(512) void k_bsort(unsigned int* __restrict__ stage,
                                               const int* __restrict__ bcursor,
                                               int* __restrict__ row_start,
                                               int* __restrict__ deg) {
    __shared__ int off[256];
    __shared__ int cur[256];
    __shared__ unsigned int out[CAP];
    const int b = blockIdx.x;
    int cnt = bcursor[b];
    if (cnt > CAP) cnt = CAP;
    const int s = b * CAP;
    const int tid = threadIdx.x;

    if (tid < 256) cur[tid] = 0;
    __syncthreads();
    for (int i = tid; i < cnt; i += 512)
        atomicAdd(&cur[stage[s + i] >> 17], 1);
    __syncthreads();
    int v = 0;
    if (tid < 256) {
        v = cur[tid];
        off[tid] = v;
    }
    __syncthreads();
    for (int d = 1; d < 256; d <<= 1) {
        int t = 0;
        if (tid < 256 && tid >= d) t = off[tid - d];
        __syncthreads();
        if (tid < 256) off[tid] += t;
        __syncthreads();
    }
    if (tid < 256) {
        int ex = off[tid] - v;
        off[tid] = ex;
        cur[tid] = 0;
        int node = b * 256 + tid;
        if (node < N_NODES) {
            row_start[node] = s + ex;
            deg[node] = v;
        }
    }
    __syncthreads();

    for (int i = tid; i < cnt; i += 512) {
        unsigned int p = stage[s + i];
        int l = p >> 17;
        int pos = off[l] + atomicAdd(&cur[l], 1);
        out[pos] = p & 0x1FFFFu;
    }
    __syncthreads();
    for (int i = tid; i < cnt; i += 512)
        stage[s + i] = out[i];
}

// ---------------------------------------------------------------------------
// Layer 1 fused: one wave per node, 8 neighbors per load, shfl-reduce,
// 8->64 MLP with weights in regs, write h1 as fp16.
// ---------------------------------------------------------------------------
__global__ __launch_bounds__(256) void layer1(
    const float* __restrict__ x, const int* __restrict__ row_start,
    const int* __restrict__ deg, const int* __restrict__ csr,
    const float* __restrict__ W1l, const float* __restrict__ b1,
    const float* __restrict__ W1r, __half* __restrict__ h1h) {
    const int lane = threadIdx.x & 63;
    const int g = lane >> 3;
    const int sub = lane & 7;

    float wl1[8], wr1[8];
#pragma unroll
    for (int k = 0; k < 8; k++) {
        wl1[k] = W1l[k * 64 + lane];
        wr1[k] = W1r[k * 64 + lane];
    }
    float bv = b1[lane];
    asm volatile("" ::: "memory");

    const int gwid = (blockIdx.x * blockDim.x + threadIdx.x) >> 6;
    const int nwaves = (gridDim.x * blockDim.x) >> 6;

    for (int node = gwid; node < N_NODES; node += nwaves) {
        int rs = row_start[node];
        int dg = deg[node];
        int re = rs + dg;
        float acc = 0.0f;
        int t = rs;
        for (; t + 16 <= re; t += 16) {
            int i0 = csr[t + g];
            int i1 = csr[t + 8 + g];
            acc += x[i0 * 8 + sub] + x[i1 * 8 + sub];
        }
        for (; t + 8 <= re; t += 8) {
            int i0 = csr[t + g];
            acc += x[i0 * 8 + sub];
        }
        int r = re - t;
        if (r > 0) {
            int ii = csr[(t + g < re) ? (t + g) : (re - 1)];
            float v = x[ii * 8 + sub];
            if (g < r) acc += v;
        }
        acc += __shfl_xor(acc, 8);
        acc += __shfl_xor(acc, 16);
        acc += __shfl_xor(acc, 32);
        float inv = 1.0f / fmaxf((float)dg, 1.0f);
        float mean = acc * inv;
        float xself = x[node * 8 + sub];
        float m[8], xk[8];
#pragma unroll
        for (int k = 0; k < 8; k++) {
            m[k]  = __shfl(mean, k);
            xk[k] = __shfl(xself, k);
        }
        float a = bv;
#pragma unroll
        for (int k = 0; k < 8; k++)
            a += m[k] * wl1[k] + xk[k] * wr1[k];
        h1h[node * 64 + lane] = __float2half(fmaxf(a, 0.0f));
    }
}

// ---------------------------------------------------------------------------
// Layer 2 aggregation: 8-lane node groups — 8 INDEPENDENT gather chains per
// wave (vs 1 in the wave-per-node design). Lane owns feature chunk sub*8..
// sub*8+7 (uint4 = 16B); group's 8 lanes cover the 128B row. One neighbor
// per group-iteration, x2 unrolled -> 16 rows in flight per wave. No shfl
// reduce; coalesced 128B row writes. Consecutive groups read adjacent csr
// segments (nodes are contiguous post-sort).
// ---------------------------------------------------------------------------
__global__ __launch_bounds__(256) void agg2(
    const __half* __restrict__ h1h, const int* __restrict__ row_start,
    const int* __restrict__ deg, const int* __restrict__ csr,
    __half* __restrict__ mean2h) {
    const int sub = threadIdx.x & 7;
    const int gg = (blockIdx.x * blockDim.x + threadIdx.x) >> 3;
    const int ngrp = (gridDim.x * blockDim.x) >> 3;

    for (int node = gg; node < N_NODES; node += ngrp) {
        int rs = row_start[node];
        int dg = deg[node];
        int re = rs + dg;
        float acc[8];
#pragma unroll
        for (int j = 0; j < 8; j++) acc[j] = 0.0f;
        int t = rs;
        for (; t + 2 <= re; t += 2) {
            int s0 = csr[t];
            int s1 = csr[t + 1];
            uint4 a = *(const uint4*)(h1h + (size_t)s0 * 64 + sub * 8);
            uint4 b = *(const uint4*)(h1h + (size_t)s1 * 64 + sub * 8);
            h8_add(a, acc);
            h8_add(b, acc);
        }
        if (t < re) {
            int s0 = csr[t];
            uint4 a = *(const uint4*)(h1h + (size_t)s0 * 64 + sub * 8);
            h8_add(a, acc);
        }
        float inv = 1.0f / fmaxf((float)dg, 1.0f);
        __half2 o0 = __floats2half2_rn(acc[0] * inv, acc[1] * inv);
        __half2 o1 = __floats2half2_rn(acc[2] * inv, acc[3] * inv);
        __half2 o2 = __floats2half2_rn(acc[4] * inv, acc[5] * inv);
        __half2 o3 = __floats2half2_rn(acc[6] * inv, acc[7] * inv);
        uint4 pk;
        pk.x = *(unsigned int*)&o0;
        pk.y = *(unsigned int*)&o1;
        pk.z = *(unsigned int*)&o2;
        pk.w = *(unsigned int*)&o3;
        *(uint4*)(mean2h + (size_t)node * 64 + sub * 8) = pk;
    }
}

// ---------------------------------------------------------------------------
// Layer 2 MLP + global mean pool. Quartet-per-wave, double-buffered private
// LDS staging, packed half2 weights via v_dot2_f32_f16. (Kept SEPARATE from
// agg2: fusing demotes the 64 weight VGPRs to scratch — round-8 lesson.)
// ---------------------------------------------------------------------------
__global__ __launch_bounds__(256) void mlp2(
    const __half* __restrict__ mean2h, const __half* __restrict__ h1h,
    const float* __restrict__ W2l, const float* __restrict__ b2,
    const float* __restrict__ W2r, float* __restrict__ gsum) {
    __shared__ __align__(16) unsigned short sh[4][2][512];
    __shared__ float part[4][64];
    const int tid = threadIdx.x;
    const int lane = tid & 63;
    const int w = tid >> 6;

    f16x2 w2[64];
#pragma unroll
    for (int k2 = 0; k2 < 32; k2++) {
        f16x2 t;
        t.x = (_Float16)W2l[(2 * k2) * 64 + lane];
        t.y = (_Float16)W2l[(2 * k2 + 1) * 64 + lane];
        w2[k2] = t;
        f16x2 u;
        u.x = (_Float16)W2r[(2 * k2) * 64 + lane];
        u.y = (_Float16)W2r[(2 * k2 + 1) * 64 + lane];
        w2[32 + k2] = u;
    }
    float bv = b2[lane];
    asm volatile("" ::: "memory");

    const int n = lane >> 4;
    const int r = (lane >> 3) & 1;
    const int c = lane & 7;
    const __half* sbase = r ? h1h : mean2h;

    const int gwid = (blockIdx.x * blockDim.x + tid) >> 6;
    const int nwaves = (gridDim.x * blockDim.x) >> 6;
    float pool = 0.0f;

    int q = gwid;
    uint4 cur = {0, 0, 0, 0};
    if (q < NQ)
        cur = *(const uint4*)(sbase + (size_t)(q * 4 + n) * 64 + c * 8);
    int p = 0;
    while (q < NQ) {
        *(uint4*)&sh[w][p][lane * 8] = cur;
        int qn = q + nwaves;
        uint4 nxt = {0, 0, 0, 0};
        if (qn < NQ)
            nxt = *(const uint4*)(sbase + (size_t)(qn * 4 + n) * 64 + c * 8);
        const uint4* rows = (const uint4*)&sh[w][p][0];
        float a0 = bv, a1 = bv, a2 = bv, a3 = bv;
#pragma unroll
        for (int cc = 0; cc < 16; cc++) {
            uint4 r0 = rows[cc];
            uint4 r1 = rows[16 + cc];
            uint4 r2 = rows[32 + cc];
            uint4 r3 = rows[48 + cc];
            f16x2 wa = w2[cc * 4 + 0], wb = w2[cc * 4 + 1];
            f16x2 wc = w2[cc * 4 + 2], wd = w2[cc * 4 + 3];
            a0 = DOT2(uf2(r0.x), wa, a0); a0 = DOT2(uf2(r0.y), wb, a0);
            a0 = DOT2(uf2(r0.z), wc, a0); a0 = DOT2(uf2(r0.w), wd, a0);
            a1 = DOT2(uf2(r1.x), wa, a1); a1 = DOT2(uf2(r1.y), wb, a1);
            a1 = DOT2(uf2(r1.z), wc, a1); a1 = DOT2(uf2(r1.w), wd, a1);
            a2 = DOT2(uf2(r2.x), wa, a2); a2 = DOT2(uf2(r2.y), wb, a2);
            a2 = DOT2(uf2(r2.z), wc, a2); a2 = DOT2(uf2(r2.w), wd, a2);
            a3 = DOT2(uf2(r3.x), wa, a3); a3 = DOT2(uf2(r3.y), wb, a3);
            a3 = DOT2(uf2(r3.z), wc, a3); a3 = DOT2(uf2(r3.w), wd, a3);
        }
        pool += fmaxf(a0, 0.0f) + fmaxf(a1, 0.0f) +
                fmaxf(a2, 0.0f) + fmaxf(a3, 0.0f);
        cur = nxt;
        p ^= 1;
        q = qn;
    }

    part[w][lane] = pool;
    __syncthreads();
    if (tid < 64)
        atomicAdd(&gsum[tid],
                  part[0][tid] + part[1][tid] + part[2][tid] + part[3][tid]);
}

// ---------------------------------------------------------------------------
// Head
// ---------------------------------------------------------------------------
__global__ void head(const float* __restrict__ gsum,
                     const float* __restrict__ fc1W, const float* __restrict__ fc1b,
                     const float* __restrict__ fc2W, const float* __restrict__ fc2b,
                     float* __restrict__ out) {
    __shared__ float g[64];
    __shared__ float a1[64];
    __shared__ float a2[10];
    int j = threadIdx.x;
    g[j] = gsum[j] * (1.0f / (float)N_NODES);
    __syncthreads();
    float acc = fc1b[j];
    for (int k = 0; k < 64; k++) acc += g[k] * fc1W[k * 64 + j];
    a1[j] = fmaxf(acc, 0.0f);
    __syncthreads();
    if (j < 10) {
        float acc2 = fc2b[j];
        for (int k = 0; k < 64; k++) acc2 += a1[k] * fc2W[k * 10 + j];
        a2[j] = acc2;
    }
    __syncthreads();
    if (j == 0) {
        float mx = -1e30f;
        for (int i = 0; i < 10; i++) mx = fmaxf(mx, a2[i]);
        float s = 0.0f;
        float e[10];
        for (int i = 0; i < 10; i++) {
            e[i] = expf(a2[i] - mx);
            s += e[i];
        }
        float invs = 1.0f / s;
        for (int i = 0; i < 10; i++) out[i] = e[i] * invs;
    }
}

extern "C" void kernel_launch(void* const* d_in, const int* in_sizes, int n_in,
                              void* d_out, int out_size, void* d_ws, size_t ws_size,
                              hipStream_t stream) {
    const float* x    = (const float*)d_in[0];
    const int*   ei   = (const int*)d_in[1];
    const float* W1l  = (const float*)d_in[2];
    const float* b1   = (const float*)d_in[3];
    const float* W1r  = (const float*)d_in[4];
    const float* W2l  = (const float*)d_in[5];
    const float* b2   = (const float*)d_in[6];
    const float* W2r  = (const float*)d_in[7];
    const float* fc1W = (const float*)d_in[8];
    const float* fc1b = (const float*)d_in[9];
    const float* fc2W = (const float*)d_in[10];
    const float* fc2b = (const float*)d_in[11];
    float* out = (float*)d_out;

    const int* src = ei;
    const int* dst = ei + N_EDGES;

    // workspace layout:
    //   h1h (N*64 half, 12.8MB) | stage/csr (NBUCK*CAP uint, 12.8MB) |
    //   mean2h (N*64 half, 12.8MB) | row_start (N) | deg (N) | bcursor (NB) | gsum
    __half* h1h    = (__half*)d_ws;
    unsigned int* stage = (unsigned int*)(h1h + (size_t)N_NODES * 64);
    int* csr       = (int*)stage;   // sorted in place by k_bsort
    __half* mean2h = (__half*)(stage + (size_t)NBUCK * CAP);
    int* row_start = (int*)(mean2h + (size_t)N_NODES * 64);
    int* deg       = row_start + N_NODES;
    int* bcursor   = deg + N_NODES;
    float* gsum    = (float*)(bcursor + NBUCK);

    // zero bcursor + gsum (adjacent)
    k_zero<<<1, 256, 0, stream>>>(bcursor, NBUCK + 64);

    k_stage<<<512, 256, 0, stream>>>(src, dst, bcursor, stage);
    k_bsort<<<NBUCK, 512, 0, stream>>>(stage, bcursor, row_start, deg);
    layer1<<<2048, 256, 0, stream>>>(x, row_start, deg, csr, W1l, b1, W1r, h1h);
    agg2<<<1024, 256, 0, stream>>>(h1h, row_start, deg, csr, mean2h);
    mlp2<<<768, 256, 0, stream>>>(mean2h, h1h, W2l, b2, W2r, gsum);
    head<<<1, 64, 0, stream>>>(gsum, fc1W, fc1b, fc2W, fc2b, out);
}

// Round 18
// 132.406 us; speedup vs baseline: 2.2287x; 1.1318x over previous
//
#include <hip/hip_runtime.h>
#include <hip/hip_bf16.h>
#include <hip/hip_fp16.h>

#define N_NODES 100000
#define N_EDGES 1600000
#define NBUCK ((N_NODES + 255) >> 8)   // 391 buckets of 256 nodes
#define CAP 8192                        // fixed region capacity per bucket (mean ~4096)
#define NMT (N_NODES / 16)              // 6250 M-tiles (MFMA mlp2)

typedef _Float16 f16x8 __attribute__((ext_vector_type(8)));
typedef float f32x4 __attribute__((ext_vector_type(4)));

__device__ inline float2 h2_to_f2(unsigned int u) {
    __half2 h = *reinterpret_cast<__half2*>(&u);
    return __half22float2(h);
}

// ---------------------------------------------------------------------------
// Zero bcursor + gsum (tiny; NOT hipMemsetAsync — rocclr blit node overhead)
// ---------------------------------------------------------------------------
__global__ void k_zero(int* __restrict__ p, int n) {
    for (int i = threadIdx.x; i < n; i += 256) p[i] = 0;
}

// ---------------------------------------------------------------------------
// CSR build pass 1: stage edges into fixed-capacity bucket regions.
// ---------------------------------------------------------------------------
__global__ __launch_bounds__(256) void k_stage(const int* __restrict__ src,
                                               const int* __restrict__ dst,
                                               int* __restrict__ bcursor,
                                               unsigned int* __restrict__ stage) {
    __shared__ int h[NBUCK];
    __shared__ int base[NBUCK];
    __shared__ int cur[NBUCK];
    const int epb = (N_EDGES + gridDim.x - 1) / gridDim.x;
    const int c0 = blockIdx.x * epb;
    const int c1 = (c0 + epb < N_EDGES) ? (c0 + epb) : N_EDGES;

    for (int i = threadIdx.x; i < NBUCK; i += 256) { h[i] = 0; cur[i] = 0; }
    __syncthreads();
    for (int e = c0 + threadIdx.x; e < c1; e += 256)
        atomicAdd(&h[dst[e] >> 8], 1);
    __syncthreads();
    for (int i = threadIdx.x; i < NBUCK; i += 256)
        base[i] = h[i] ? atomicAdd(&bcursor[i], h[i]) : 0;
    __syncthreads();
    for (int e = c0 + threadIdx.x; e < c1; e += 256) {
        int d = dst[e];
        int b = d >> 8;
        int pos = base[b] + atomicAdd(&cur[b], 1);
        if (pos < CAP)  // overflow guard (P ~ 0 for this graph)
            stage[b * CAP + pos] = ((unsigned int)(d & 255) << 17) | (unsigned int)src[e];
    }
}

// ---------------------------------------------------------------------------
// CSR build pass 2: one block (512 thr) per bucket; LDS counting-sort IN
// PLACE. Emits row_start[node] = b*CAP + local_excl_offset and deg[node].
// ---------------------------------------------------------------------------
__global__ __launch_bounds__(512) void k_bsort(unsigned int* __restrict__ stage,
                                               const int* __restrict__ bcursor,
                                               int* __restrict__ row_start,
                                               int* __restrict__ deg) {
    __shared__ int off[256];
    __shared__ int cur[256];
    __shared__ unsigned int out[CAP];
    const int b = blockIdx.x;
    int cnt = bcursor[b];
    if (cnt > CAP) cnt = CAP;
    const int s = b * CAP;
    const int tid = threadIdx.x;

    if (tid < 256) cur[tid] = 0;
    __syncthreads();
    for (int i = tid; i < cnt; i += 512)
        atomicAdd(&cur[stage[s + i] >> 17], 1);
    __syncthreads();
    int v = 0;
    if (tid < 256) {
        v = cur[tid];
        off[tid] = v;
    }
    __syncthreads();
    for (int d = 1; d < 256; d <<= 1) {
        int t = 0;
        if (tid < 256 && tid >= d) t = off[tid - d];
        __syncthreads();
        if (tid < 256) off[tid] += t;
        __syncthreads();
    }
    if (tid < 256) {
        int ex = off[tid] - v;
        off[tid] = ex;
        cur[tid] = 0;
        int node = b * 256 + tid;
        if (node < N_NODES) {
            row_start[node] = s + ex;
            deg[node] = v;
        }
    }
    __syncthreads();

    for (int i = tid; i < cnt; i += 512) {
        unsigned int p = stage[s + i];
        int l = p >> 17;
        int pos = off[l] + atomicAdd(&cur[l], 1);
        out[pos] = p & 0x1FFFFu;
    }
    __syncthreads();
    for (int i = tid; i < cnt; i += 512)
        stage[s + i] = out[i];
}

// ---------------------------------------------------------------------------
// Layer 1 fused: one wave per node, 8 neighbors per load, shfl-reduce,
// 8->64 MLP with weights in regs, write h1 as fp16.
// ---------------------------------------------------------------------------
__global__ __launch_bounds__(256) void layer1(
    const float* __restrict__ x, const int* __restrict__ row_start,
    const int* __restrict__ deg, const int* __restrict__ csr,
    const float* __restrict__ W1l, const float* __restrict__ b1,
    const float* __restrict__ W1r, __half* __restrict__ h1h) {
    const int lane = threadIdx.x & 63;
    const int g = lane >> 3;
    const int sub = lane & 7;

    float wl1[8], wr1[8];
#pragma unroll
    for (int k = 0; k < 8; k++) {
        wl1[k] = W1l[k * 64 + lane];
        wr1[k] = W1r[k * 64 + lane];
    }
    float bv = b1[lane];
    asm volatile("" ::: "memory");

    const int gwid = (blockIdx.x * blockDim.x + threadIdx.x) >> 6;
    const int nwaves = (gridDim.x * blockDim.x) >> 6;

    for (int node = gwid; node < N_NODES; node += nwaves) {
        int rs = row_start[node];
        int dg = deg[node];
        int re = rs + dg;
        float acc = 0.0f;
        int t = rs;
        for (; t + 16 <= re; t += 16) {
            int i0 = csr[t + g];
            int i1 = csr[t + 8 + g];
            acc += x[i0 * 8 + sub] + x[i1 * 8 + sub];
        }
        for (; t + 8 <= re; t += 8) {
            int i0 = csr[t + g];
            acc += x[i0 * 8 + sub];
        }
        int r = re - t;
        if (r > 0) {
            int ii = csr[(t + g < re) ? (t + g) : (re - 1)];
            float v = x[ii * 8 + sub];
            if (g < r) acc += v;
        }
        acc += __shfl_xor(acc, 8);
        acc += __shfl_xor(acc, 16);
        acc += __shfl_xor(acc, 32);
        float inv = 1.0f / fmaxf((float)dg, 1.0f);
        float mean = acc * inv;
        float xself = x[node * 8 + sub];
        float m[8], xk[8];
#pragma unroll
        for (int k = 0; k < 8; k++) {
            m[k]  = __shfl(mean, k);
            xk[k] = __shfl(xself, k);
        }
        float a = bv;
#pragma unroll
        for (int k = 0; k < 8; k++)
            a += m[k] * wl1[k] + xk[k] * wr1[k];
        h1h[node * 64 + lane] = __float2half(fmaxf(a, 0.0f));
    }
}

// ---------------------------------------------------------------------------
// Layer 2 aggregation (round-12 proven version): one wave per node, fp16
// rows, 4 neighbors per load, 2x unrolled. Output mean2 as fp16.
// ---------------------------------------------------------------------------
__global__ __launch_bounds__(256) void agg2(
    const __half* __restrict__ h1h, const int* __restrict__ row_start,
    const int* __restrict__ deg, const int* __restrict__ csr,
    __half* __restrict__ mean2h) {
    const int lane = threadIdx.x & 63;
    const int g = lane >> 4;
    const int sub = lane & 15;

    const int gwid = (blockIdx.x * blockDim.x + threadIdx.x) >> 6;
    const int nwaves = (gridDim.x * blockDim.x) >> 6;

    for (int node = gwid; node < N_NODES; node += nwaves) {
        int rs = row_start[node];
        int dg = deg[node];
        int re = rs + dg;
        float4 acc = {0.f, 0.f, 0.f, 0.f};
        int t = rs;
        for (; t + 8 <= re; t += 8) {
            int i0 = csr[t + g];
            int i1 = csr[t + 4 + g];
            uint2 a = *(const uint2*)(h1h + i0 * 64 + sub * 4);
            uint2 b = *(const uint2*)(h1h + i1 * 64 + sub * 4);
            float2 a0 = h2_to_f2(a.x), a1 = h2_to_f2(a.y);
            float2 b0 = h2_to_f2(b.x), b1 = h2_to_f2(b.y);
            acc.x += a0.x + b0.x; acc.y += a0.y + b0.y;
            acc.z += a1.x + b1.x; acc.w += a1.y + b1.y;
        }
        for (; t + 4 <= re; t += 4) {
            int i0 = csr[t + g];
            uint2 a = *(const uint2*)(h1h + i0 * 64 + sub * 4);
            float2 a0 = h2_to_f2(a.x), a1 = h2_to_f2(a.y);
            acc.x += a0.x; acc.y += a0.y; acc.z += a1.x; acc.w += a1.y;
        }
        int r = re - t;
        if (r > 0) {
            int ii = csr[(t + g < re) ? (t + g) : (re - 1)];
            uint2 a = *(const uint2*)(h1h + ii * 64 + sub * 4);
            if (g < r) {
                float2 a0 = h2_to_f2(a.x), a1 = h2_to_f2(a.y);
                acc.x += a0.x; acc.y += a0.y; acc.z += a1.x; acc.w += a1.y;
            }
        }
#pragma unroll
        for (int m = 16; m <= 32; m <<= 1) {
            acc.x += __shfl_xor(acc.x, m);
            acc.y += __shfl_xor(acc.y, m);
            acc.z += __shfl_xor(acc.z, m);
            acc.w += __shfl_xor(acc.w, m);
        }
        float inv = 1.0f / fmaxf((float)dg, 1.0f);
        if (lane < 16) {
            __half2 o0 = __floats2half2_rn(acc.x * inv, acc.y * inv);
            __half2 o1 = __floats2half2_rn(acc.z * inv, acc.w * inv);
            uint2 pk;
            pk.x = *(unsigned int*)&o0;
            pk.y = *(unsigned int*)&o1;
            *(uint2*)(mean2h + node * 64 + sub * 4) = pk;
        }
    }
}

// ---------------------------------------------------------------------------
// Layer 2 MLP + global mean pool via MFMA 16x16x32 f16 (gfx950-verified
// intrinsic, used UNconditionally — __has_builtin guards caused a
// host/device kernel-set mismatch -> invalid device function in R16/R17).
// C = [mean|h1][100k x 128] @ W[128 x 64] + b2; relu; column-sum -> gsum.
// M-tile = 16 nodes; 4 K-chunks of 32 (c=0,1: mean; c=2,3: h1); 4 N-tiles.
// A/B share the (grp,j)->k map (k = grp*8+j within chunk): contraction is
// invariant under a shared k-permutation; only row/col = lane&15 must match
// HW. C/D: col=lane&15, row=(lane>>4)*4+reg (m89-verified).
// ---------------------------------------------------------------------------
__global__ __launch_bounds__(256) void mlp2_mfma(
    const __half* __restrict__ mean2h, const __half* __restrict__ h1h,
    const float* __restrict__ W2l, const float* __restrict__ b2,
    const float* __restrict__ W2r, float* __restrict__ gsum) {
    __shared__ float part[4][64];
    const int tid = threadIdx.x;
    const int lane = tid & 63;
    const int w = tid >> 6;
    const int row16 = lane & 15;
    const int grp = lane >> 4;

    // B fragments: bf[c][nt], element j = W[koff+j][nt*16+row16],
    // koff = (c&1)*32 + grp*8; c<2 -> W2l, c>=2 -> W2r.
    f16x8 bf[4][4];
#pragma unroll
    for (int c = 0; c < 4; c++) {
        const float* Wsrc = (c < 2) ? W2l : W2r;
        int koff = (c & 1) * 32 + grp * 8;
#pragma unroll
        for (int nt = 0; nt < 4; nt++) {
            f16x8 t;
#pragma unroll
            for (int j = 0; j < 8; j++)
                t[j] = (_Float16)Wsrc[(koff + j) * 64 + nt * 16 + row16];
            bf[c][nt] = t;
        }
    }
    float bv[4];
#pragma unroll
    for (int nt = 0; nt < 4; nt++) bv[nt] = b2[nt * 16 + row16];
    asm volatile("" ::: "memory");  // pin weights in registers

    const int gwid = (blockIdx.x * blockDim.x + tid) >> 6;
    const int nwaves = (gridDim.x * blockDim.x) >> 6;
    float pool[4] = {0.f, 0.f, 0.f, 0.f};

    for (int mt = gwid; mt < NMT; mt += nwaves) {
        int n0 = mt * 16;
        const __half* am = mean2h + (size_t)(n0 + row16) * 64 + grp * 8;
        const __half* ah = h1h    + (size_t)(n0 + row16) * 64 + grp * 8;
        f16x8 af[4];
        af[0] = *(const f16x8*)(am);
        af[1] = *(const f16x8*)(am + 32);
        af[2] = *(const f16x8*)(ah);
        af[3] = *(const f16x8*)(ah + 32);
#pragma unroll
        for (int nt = 0; nt < 4; nt++) {
            f32x4 acc = {bv[nt], bv[nt], bv[nt], bv[nt]};
#pragma unroll
            for (int c = 0; c < 4; c++)
                acc = __builtin_amdgcn_mfma_f32_16x16x32_f16(af[c], bf[c][nt],
                                                             acc, 0, 0, 0);
            // C: rows = nodes n0 + grp*4 + reg at col nt*16+row16: relu+pool
            pool[nt] += fmaxf(acc[0], 0.f) + fmaxf(acc[1], 0.f) +
                        fmaxf(acc[2], 0.f) + fmaxf(acc[3], 0.f);
        }
    }

    // combine the 4 row-groups (same col, disjoint node subsets)
#pragma unroll
    for (int nt = 0; nt < 4; nt++) {
        pool[nt] += __shfl_xor(pool[nt], 16);
        pool[nt] += __shfl_xor(pool[nt], 32);
    }
    if (lane < 16) {
#pragma unroll
        for (int nt = 0; nt < 4; nt++)
            part[w][nt * 16 + row16] = pool[nt];
    }
    __syncthreads();
    if (tid < 64)
        atomicAdd(&gsum[tid],
                  part[0][tid] + part[1][tid] + part[2][tid] + part[3][tid]);
}

// ---------------------------------------------------------------------------
// Head
// ---------------------------------------------------------------------------
__global__ void head(const float* __restrict__ gsum,
                     const float* __restrict__ fc1W, const float* __restrict__ fc1b,
                     const float* __restrict__ fc2W, const float* __restrict__ fc2b,
                     float* __restrict__ out) {
    __shared__ float g[64];
    __shared__ float a1[64];
    __shared__ float a2[10];
    int j = threadIdx.x;
    g[j] = gsum[j] * (1.0f / (float)N_NODES);
    __syncthreads();
    float acc = fc1b[j];
    for (int k = 0; k < 64; k++) acc += g[k] * fc1W[k * 64 + j];
    a1[j] = fmaxf(acc, 0.0f);
    __syncthreads();
    if (j < 10) {
        float acc2 = fc2b[j];
        for (int k = 0; k < 64; k++) acc2 += a1[k] * fc2W[k * 10 + j];
        a2[j] = acc2;
    }
    __syncthreads();
    if (j == 0) {
        float mx = -1e30f;
        for (int i = 0; i < 10; i++) mx = fmaxf(mx, a2[i]);
        float s = 0.0f;
        float e[10];
        for (int i = 0; i < 10; i++) {
            e[i] = expf(a2[i] - mx);
            s += e[i];
        }
        float invs = 1.0f / s;
        for (int i = 0; i < 10; i++) out[i] = e[i] * invs;
    }
}

extern "C" void kernel_launch(void* const* d_in, const int* in_sizes, int n_in,
                              void* d_out, int out_size, void* d_ws, size_t ws_size,
                              hipStream_t stream) {
    const float* x    = (const float*)d_in[0];
    const int*   ei   = (const int*)d_in[1];
    const float* W1l  = (const float*)d_in[2];
    const float* b1   = (const float*)d_in[3];
    const float* W1r  = (const float*)d_in[4];
    const float* W2l  = (const float*)d_in[5];
    const float* b2   = (const float*)d_in[6];
    const float* W2r  = (const float*)d_in[7];
    const float* fc1W = (const float*)d_in[8];
    const float* fc1b = (const float*)d_in[9];
    const float* fc2W = (const float*)d_in[10];
    const float* fc2b = (const float*)d_in[11];
    float* out = (float*)d_out;

    const int* src = ei;
    const int* dst = ei + N_EDGES;

    // workspace layout:
    //   h1h (N*64 half, 12.8MB) | stage/csr (NBUCK*CAP uint, 12.8MB) |
    //   mean2h (N*64 half, 12.8MB) | row_start (N) | deg (N) | bcursor (NB) | gsum
    __half* h1h    = (__half*)d_ws;
    unsigned int* stage = (unsigned int*)(h1h + (size_t)N_NODES * 64);
    int* csr       = (int*)stage;   // sorted in place by k_bsort
    __half* mean2h = (__half*)(stage + (size_t)NBUCK * CAP);
    int* row_start = (int*)(mean2h + (size_t)N_NODES * 64);
    int* deg       = row_start + N_NODES;
    int* bcursor   = deg + N_NODES;
    float* gsum    = (float*)(bcursor + NBUCK);

    // zero bcursor + gsum (adjacent)
    k_zero<<<1, 256, 0, stream>>>(bcursor, NBUCK + 64);

    k_stage<<<512, 256, 0, stream>>>(src, dst, bcursor, stage);
    k_bsort<<<NBUCK, 512, 0, stream>>>(stage, bcursor, row_start, deg);
    layer1<<<2048, 256, 0, stream>>>(x, row_start, deg, csr, W1l, b1, W1r, h1h);
    agg2<<<2048, 256, 0, stream>>>(h1h, row_start, deg, csr, mean2h);
    mlp2_mfma<<<512, 256, 0, stream>>>(mean2h, h1h, W2l, b2, W2r, gsum);
    head<<<1, 64, 0, stream>>>(gsum, fc1W, fc1b, fc2W, fc2b, out);
}

// Round 19
// 126.661 us; speedup vs baseline: 2.3298x; 1.0454x over previous
//
#include <hip/hip_runtime.h>
#include <hip/hip_bf16.h>
#include <hip/hip_fp16.h>

#define N_NODES 100000
#define N_EDGES 1600000
#define NBUCK ((N_NODES + 255) >> 8)   // 391 buckets of 256 nodes
#define CAP 8192                        // fixed region capacity per bucket (mean ~4096)
#define NMT (N_NODES / 16)              // 6250 M-tiles (MFMA mlp2)
#define SBLK 512                        // k_stage blocks
#define SCHUNK ((N_EDGES + SBLK - 1) / SBLK)  // 3125 edges per block

typedef _Float16 f16x8 __attribute__((ext_vector_type(8)));
typedef float f32x4 __attribute__((ext_vector_type(4)));

__device__ inline float2 h2_to_f2(unsigned int u) {
    __half2 h = *reinterpret_cast<__half2*>(&u);
    return __half22float2(h);
}

// ---------------------------------------------------------------------------
// Zero bcursor + gsum (tiny; NOT hipMemsetAsync — rocclr blit node overhead)
// ---------------------------------------------------------------------------
__global__ void k_zero(int* __restrict__ p, int n) {
    for (int i = threadIdx.x; i < n; i += 256) p[i] = 0;
}

// ---------------------------------------------------------------------------
// CSR build pass 1 (v2): stage edges into fixed-capacity bucket regions with
// LDS-GROUPED COALESCED WRITES. Per block: count -> LDS scan -> one global
// reservation atomic per (block,bucket) -> scatter payload into bucket-
// grouped LDS buffer (+ global dest index) -> linear write-out (consecutive
// threads hit consecutive addresses within each bucket run). Kills the ~16x
// write-line amplification of direct scattering.
// ---------------------------------------------------------------------------
__global__ __launch_bounds__(512) void k_stage(const int* __restrict__ src,
                                               const int* __restrict__ dst,
                                               int* __restrict__ bcursor,
                                               unsigned int* __restrict__ stage) {
    __shared__ int h[512];              // padded per-bucket counts
    __shared__ int loc[512];            // exclusive scan (local run starts)
    __shared__ int base[NBUCK];         // global run starts (within region)
    __shared__ int cur[NBUCK];          // fill cursors
    __shared__ unsigned int buf[SCHUNK];  // payload, grouped by bucket
    __shared__ int gidx[SCHUNK];          // global dest index per slot
    const int tid = threadIdx.x;
    const int c0 = blockIdx.x * SCHUNK;
    const int c1 = (c0 + SCHUNK < N_EDGES) ? (c0 + SCHUNK) : N_EDGES;

    h[tid] = 0;
    if (tid < NBUCK) cur[tid] = 0;
    __syncthreads();

    // pass 1: per-bucket counts
    for (int e = c0 + tid; e < c1; e += 512)
        atomicAdd(&h[dst[e] >> 8], 1);
    __syncthreads();

    // inclusive Hillis-Steele scan over 512 (NBUCK padded)
    int v = h[tid];
    loc[tid] = v;
    __syncthreads();
    for (int d = 1; d < 512; d <<= 1) {
        int t = (tid >= d) ? loc[tid - d] : 0;
        __syncthreads();
        loc[tid] += t;
        __syncthreads();
    }
    int inc = loc[tid];
    __syncthreads();
    loc[tid] = inc - v;   // exclusive
    if (tid < NBUCK && v > 0) base[tid] = atomicAdd(&bcursor[tid], v);
    __syncthreads();

    // pass 2: scatter into LDS grouped by bucket; record global destination
    for (int e = c0 + tid; e < c1; e += 512) {
        int d = dst[e];
        int b = d >> 8;
        int pos = loc[b] + atomicAdd(&cur[b], 1);
        buf[pos] = ((unsigned int)(d & 255) << 17) | (unsigned int)src[e];
        int gpos = base[b] + (pos - loc[b]);
        gidx[pos] = (gpos < CAP) ? (b * CAP + gpos) : -1;  // overflow guard
    }
    __syncthreads();

    // pass 3: write-out (consecutive i within a run -> consecutive addresses)
    const int cnt = c1 - c0;
    for (int i = tid; i < cnt; i += 512) {
        int g = gidx[i];
        if (g >= 0) stage[g] = buf[i];
    }
}

// ---------------------------------------------------------------------------
// CSR build pass 2: one block (512 thr) per bucket; LDS counting-sort IN
// PLACE. Emits row_start[node] = b*CAP + local_excl_offset and deg[node].
// ---------------------------------------------------------------------------
__global__ __launch_bounds__(512) void k_bsort(unsigned int* __restrict__ stage,
                                               const int* __restrict__ bcursor,
                                               int* __restrict__ row_start,
                                               int* __restrict__ deg) {
    __shared__ int off[256];
    __shared__ int cur[256];
    __shared__ unsigned int out[CAP];
    const int b = blockIdx.x;
    int cnt = bcursor[b];
    if (cnt > CAP) cnt = CAP;
    const int s = b * CAP;
    const int tid = threadIdx.x;

    if (tid < 256) cur[tid] = 0;
    __syncthreads();
    for (int i = tid; i < cnt; i += 512)
        atomicAdd(&cur[stage[s + i] >> 17], 1);
    __syncthreads();
    int v = 0;
    if (tid < 256) {
        v = cur[tid];
        off[tid] = v;
    }
    __syncthreads();
    for (int d = 1; d < 256; d <<= 1) {
        int t = 0;
        if (tid < 256 && tid >= d) t = off[tid - d];
        __syncthreads();
        if (tid < 256) off[tid] += t;
        __syncthreads();
    }
    if (tid < 256) {
        int ex = off[tid] - v;
        off[tid] = ex;
        cur[tid] = 0;
        int node = b * 256 + tid;
        if (node < N_NODES) {
            row_start[node] = s + ex;
            deg[node] = v;
        }
    }
    __syncthreads();

    for (int i = tid; i < cnt; i += 512) {
        unsigned int p = stage[s + i];
        int l = p >> 17;
        int pos = off[l] + atomicAdd(&cur[l], 1);
        out[pos] = p & 0x1FFFFu;
    }
    __syncthreads();
    for (int i = tid; i < cnt; i += 512)
        stage[s + i] = out[i];
}

// ---------------------------------------------------------------------------
// Layer 1 fused: one wave per node, 8 neighbors per load, shfl-reduce,
// 8->64 MLP with weights in regs, write h1 as fp16.
// ---------------------------------------------------------------------------
__global__ __launch_bounds__(256) void layer1(
    const float* __restrict__ x, const int* __restrict__ row_start,
    const int* __restrict__ deg, const int* __restrict__ csr,
    const float* __restrict__ W1l, const float* __restrict__ b1,
    const float* __restrict__ W1r, __half* __restrict__ h1h) {
    const int lane = threadIdx.x & 63;
    const int g = lane >> 3;
    const int sub = lane & 7;

    float wl1[8], wr1[8];
#pragma unroll
    for (int k = 0; k < 8; k++) {
        wl1[k] = W1l[k * 64 + lane];
        wr1[k] = W1r[k * 64 + lane];
    }
    float bv = b1[lane];
    asm volatile("" ::: "memory");

    const int gwid = (blockIdx.x * blockDim.x + threadIdx.x) >> 6;
    const int nwaves = (gridDim.x * blockDim.x) >> 6;

    for (int node = gwid; node < N_NODES; node += nwaves) {
        int rs = row_start[node];
        int dg = deg[node];
        int re = rs + dg;
        float acc = 0.0f;
        int t = rs;
        for (; t + 16 <= re; t += 16) {
            int i0 = csr[t + g];
            int i1 = csr[t + 8 + g];
            acc += x[i0 * 8 + sub] + x[i1 * 8 + sub];
        }
        for (; t + 8 <= re; t += 8) {
            int i0 = csr[t + g];
            acc += x[i0 * 8 + sub];
        }
        int r = re - t;
        if (r > 0) {
            int ii = csr[(t + g < re) ? (t + g) : (re - 1)];
            float v = x[ii * 8 + sub];
            if (g < r) acc += v;
        }
        acc += __shfl_xor(acc, 8);
        acc += __shfl_xor(acc, 16);
        acc += __shfl_xor(acc, 32);
        float inv = 1.0f / fmaxf((float)dg, 1.0f);
        float mean = acc * inv;
        float xself = x[node * 8 + sub];
        float m[8], xk[8];
#pragma unroll
        for (int k = 0; k < 8; k++) {
            m[k]  = __shfl(mean, k);
            xk[k] = __shfl(xself, k);
        }
        float a = bv;
#pragma unroll
        for (int k = 0; k < 8; k++)
            a += m[k] * wl1[k] + xk[k] * wr1[k];
        h1h[node * 64 + lane] = __float2half(fmaxf(a, 0.0f));
    }
}

// ---------------------------------------------------------------------------
// Layer 2 aggregation (round-12 proven version): one wave per node, fp16
// rows, 4 neighbors per load, 2x unrolled. Output mean2 as fp16.
// ---------------------------------------------------------------------------
__global__ __launch_bounds__(256) void agg2(
    const __half* __restrict__ h1h, const int* __restrict__ row_start,
    const int* __restrict__ deg, const int* __restrict__ csr,
    __half* __restrict__ mean2h) {
    const int lane = threadIdx.x & 63;
    const int g = lane >> 4;
    const int sub = lane & 15;

    const int gwid = (blockIdx.x * blockDim.x + threadIdx.x) >> 6;
    const int nwaves = (gridDim.x * blockDim.x) >> 6;

    for (int node = gwid; node < N_NODES; node += nwaves) {
        int rs = row_start[node];
        int dg = deg[node];
        int re = rs + dg;
        float4 acc = {0.f, 0.f, 0.f, 0.f};
        int t = rs;
        for (; t + 8 <= re; t += 8) {
            int i0 = csr[t + g];
            int i1 = csr[t + 4 + g];
            uint2 a = *(const uint2*)(h1h + i0 * 64 + sub * 4);
            uint2 b = *(const uint2*)(h1h + i1 * 64 + sub * 4);
            float2 a0 = h2_to_f2(a.x), a1 = h2_to_f2(a.y);
            float2 b0 = h2_to_f2(b.x), b1 = h2_to_f2(b.y);
            acc.x += a0.x + b0.x; acc.y += a0.y + b0.y;
            acc.z += a1.x + b1.x; acc.w += a1.y + b1.y;
        }
        for (; t + 4 <= re; t += 4) {
            int i0 = csr[t + g];
            uint2 a = *(const uint2*)(h1h + i0 * 64 + sub * 4);
            float2 a0 = h2_to_f2(a.x), a1 = h2_to_f2(a.y);
            acc.x += a0.x; acc.y += a0.y; acc.z += a1.x; acc.w += a1.y;
        }
        int r = re - t;
        if (r > 0) {
            int ii = csr[(t + g < re) ? (t + g) : (re - 1)];
            uint2 a = *(const uint2*)(h1h + ii * 64 + sub * 4);
            if (g < r) {
                float2 a0 = h2_to_f2(a.x), a1 = h2_to_f2(a.y);
                acc.x += a0.x; acc.y += a0.y; acc.z += a1.x; acc.w += a1.y;
            }
        }
#pragma unroll
        for (int m = 16; m <= 32; m <<= 1) {
            acc.x += __shfl_xor(acc.x, m);
            acc.y += __shfl_xor(acc.y, m);
            acc.z += __shfl_xor(acc.z, m);
            acc.w += __shfl_xor(acc.w, m);
        }
        float inv = 1.0f / fmaxf((float)dg, 1.0f);
        if (lane < 16) {
            __half2 o0 = __floats2half2_rn(acc.x * inv, acc.y * inv);
            __half2 o1 = __floats2half2_rn(acc.z * inv, acc.w * inv);
            uint2 pk;
            pk.x = *(unsigned int*)&o0;
            pk.y = *(unsigned int*)&o1;
            *(uint2*)(mean2h + node * 64 + sub * 4) = pk;
        }
    }
}

// ---------------------------------------------------------------------------
// Layer 2 MLP + global mean pool via MFMA 16x16x32 f16 (unconditional —
// __has_builtin guards cause host/device kernel-set mismatch).
// ---------------------------------------------------------------------------
__global__ __launch_bounds__(256) void mlp2_mfma(
    const __half* __restrict__ mean2h, const __half* __restrict__ h1h,
    const float* __restrict__ W2l, const float* __restrict__ b2,
    const float* __restrict__ W2r, float* __restrict__ gsum) {
    __shared__ float part[4][64];
    const int tid = threadIdx.x;
    const int lane = tid & 63;
    const int w = tid >> 6;
    const int row16 = lane & 15;
    const int grp = lane >> 4;

    f16x8 bf[4][4];
#pragma unroll
    for (int c = 0; c < 4; c++) {
        const float* Wsrc = (c < 2) ? W2l : W2r;
        int koff = (c & 1) * 32 + grp * 8;
#pragma unroll
        for (int nt = 0; nt < 4; nt++) {
            f16x8 t;
#pragma unroll
            for (int j = 0; j < 8; j++)
                t[j] = (_Float16)Wsrc[(koff + j) * 64 + nt * 16 + row16];
            bf[c][nt] = t;
        }
    }
    float bv[4];
#pragma unroll
    for (int nt = 0; nt < 4; nt++) bv[nt] = b2[nt * 16 + row16];
    asm volatile("" ::: "memory");

    const int gwid = (blockIdx.x * blockDim.x + tid) >> 6;
    const int nwaves = (gridDim.x * blockDim.x) >> 6;
    float pool[4] = {0.f, 0.f, 0.f, 0.f};

    for (int mt = gwid; mt < NMT; mt += nwaves) {
        int n0 = mt * 16;
        const __half* am = mean2h + (size_t)(n0 + row16) * 64 + grp * 8;
        const __half* ah = h1h    + (size_t)(n0 + row16) * 64 + grp * 8;
        f16x8 af[4];
        af[0] = *(const f16x8*)(am);
        af[1] = *(const f16x8*)(am + 32);
        af[2] = *(const f16x8*)(ah);
        af[3] = *(const f16x8*)(ah + 32);
#pragma unroll
        for (int nt = 0; nt < 4; nt++) {
            f32x4 acc = {bv[nt], bv[nt], bv[nt], bv[nt]};
#pragma unroll
            for (int c = 0; c < 4; c++)
                acc = __builtin_amdgcn_mfma_f32_16x16x32_f16(af[c], bf[c][nt],
                                                             acc, 0, 0, 0);
            pool[nt] += fmaxf(acc[0], 0.f) + fmaxf(acc[1], 0.f) +
                        fmaxf(acc[2], 0.f) + fmaxf(acc[3], 0.f);
        }
    }

#pragma unroll
    for (int nt = 0; nt < 4; nt++) {
        pool[nt] += __shfl_xor(pool[nt], 16);
        pool[nt] += __shfl_xor(pool[nt], 32);
    }
    if (lane < 16) {
#pragma unroll
        for (int nt = 0; nt < 4; nt++)
            part[w][nt * 16 + row16] = pool[nt];
    }
    __syncthreads();
    if (tid < 64)
        atomicAdd(&gsum[tid],
                  part[0][tid] + part[1][tid] + part[2][tid] + part[3][tid]);
}

// ---------------------------------------------------------------------------
// Head
// ---------------------------------------------------------------------------
__global__ void head(const float* __restrict__ gsum,
                     const float* __restrict__ fc1W, const float* __restrict__ fc1b,
                     const float* __restrict__ fc2W, const float* __restrict__ fc2b,
                     float* __restrict__ out) {
    __shared__ float g[64];
    __shared__ float a1[64];
    __shared__ float a2[10];
    int j = threadIdx.x;
    g[j] = gsum[j] * (1.0f / (float)N_NODES);
    __syncthreads();
    float acc = fc1b[j];
    for (int k = 0; k < 64; k++) acc += g[k] * fc1W[k * 64 + j];
    a1[j] = fmaxf(acc, 0.0f);
    __syncthreads();
    if (j < 10) {
        float acc2 = fc2b[j];
        for (int k = 0; k < 64; k++) acc2 += a1[k] * fc2W[k * 10 + j];
        a2[j] = acc2;
    }
    __syncthreads();
    if (j == 0) {
        float mx = -1e30f;
        for (int i = 0; i < 10; i++) mx = fmaxf(mx, a2[i]);
        float s = 0.0f;
        float e[10];
        for (int i = 0; i < 10; i++) {
            e[i] = expf(a2[i] - mx);
            s += e[i];
        }
        float invs = 1.0f / s;
        for (int i = 0; i < 10; i++) out[i] = e[i] * invs;
    }
}

extern "C" void kernel_launch(void* const* d_in, const int* in_sizes, int n_in,
                              void* d_out, int out_size, void* d_ws, size_t ws_size,
                              hipStream_t stream) {
    const float* x    = (const float*)d_in[0];
    const int*   ei   = (const int*)d_in[1];
    const float* W1l  = (const float*)d_in[2];
    const float* b1   = (const float*)d_in[3];
    const float* W1r  = (const float*)d_in[4];
    const float* W2l  = (const float*)d_in[5];
    const float* b2   = (const float*)d_in[6];
    const float* W2r  = (const float*)d_in[7];
    const float* fc1W = (const float*)d_in[8];
    const float* fc1b = (const float*)d_in[9];
    const float* fc2W = (const float*)d_in[10];
    const float* fc2b = (const float*)d_in[11];
    float* out = (float*)d_out;

    const int* src = ei;
    const int* dst = ei + N_EDGES;

    // workspace layout:
    //   h1h (N*64 half, 12.8MB) | stage/csr (NBUCK*CAP uint, 12.8MB) |
    //   mean2h (N*64 half, 12.8MB) | row_start (N) | deg (N) | bcursor (NB) | gsum
    __half* h1h    = (__half*)d_ws;
    unsigned int* stage = (unsigned int*)(h1h + (size_t)N_NODES * 64);
    int* csr       = (int*)stage;   // sorted in place by k_bsort
    __half* mean2h = (__half*)(stage + (size_t)NBUCK * CAP);
    int* row_start = (int*)(mean2h + (size_t)N_NODES * 64);
    int* deg       = row_start + N_NODES;
    int* bcursor   = deg + N_NODES;
    float* gsum    = (float*)(bcursor + NBUCK);

    // zero bcursor + gsum (adjacent)
    k_zero<<<1, 256, 0, stream>>>(bcursor, NBUCK + 64);

    k_stage<<<SBLK, 512, 0, stream>>>(src, dst, bcursor, stage);
    k_bsort<<<NBUCK, 512, 0, stream>>>(stage, bcursor, row_start, deg);
    layer1<<<2048, 256, 0, stream>>>(x, row_start, deg, csr, W1l, b1, W1r, h1h);
    agg2<<<2048, 256, 0, stream>>>(h1h, row_start, deg, csr, mean2h);
    mlp2_mfma<<<512, 256, 0, stream>>>(mean2h, h1h, W2l, b2, W2r, gsum);
    head<<<1, 64, 0, stream>>>(gsum, fc1W, fc1b, fc2W, fc2b, out);
}